// Round 5
// baseline (745.758 us; speedup 1.0000x reference)
//
#include <hip/hip_runtime.h>
#include <hip/hip_bf16.h>
#include <math.h>

typedef unsigned short u16;
typedef __attribute__((ext_vector_type(8))) short bf16x8;
typedef __attribute__((ext_vector_type(4))) float f32x4;

// ---------- helpers ----------
__device__ __forceinline__ u16 f2bf(float f) {
  union { float f; unsigned u; } x; x.f = f;
  unsigned r = x.u + 0x7fffu + ((x.u >> 16) & 1u);
  return (u16)(r >> 16);
}
__device__ __forceinline__ float bf2f(u16 h) {
  union { unsigned u; float f; } x; x.u = ((unsigned)h) << 16;
  return x.f;
}
__device__ __forceinline__ float sigmf(float x) {
  x = fminf(fmaxf(x, -30.f), 30.f);
  return 1.f / (1.f + __expf(-x));
}
__device__ __forceinline__ float tanh_fast(float x) {
  x = fminf(fmaxf(x, -15.f), 15.f);
  float t = __expf(2.f * x);
  return (t - 1.f) / (t + 1.f);
}

// ---------- problem constants ----------
#define NB 4
#define DE 128
#define DO_ 512
#define HW 1560
#define THW 6240
#define NP 1664   // HW padded to 13*128
#define KP 6272   // THW padded to 49*128
#define PROP 5
#define PVSPLIT 7
#define PVKC 896  // 6272/7, = 28*32

// ---------- weight-stream GEMM: C[M,N] = A[M,K] * Bt[N,K]^T ----------
// Whole A-panel (ROWS x KTOT) staged to LDS with ONE barrier; B streamed
// from L2 directly into registers; K-loop has NO barriers -> compiler
// software-pipelines loads over MFMAs freely. Tile ROWS x 128, 4 waves,
// wave w owns cols [w*32, w*32+32).
template<int MODE, int ROWS, int KTOT>
__global__ __launch_bounds__(256)
void gemm_ws(const u16* __restrict__ A, const u16* __restrict__ Bt,
             int lda, int ldb, long a_bs, long b_bs,
             void* __restrict__ out0v, long o0_bs, int ld0,
             u16* __restrict__ out1, long o1_bs, int ld1,
             const void* __restrict__ e0v, long e0_bs,
             const void* __restrict__ e1v, long e1_bs,
             const void* __restrict__ e2v, long e2_bs,
             int nvalid, float scale)
{
  constexpr int MF = ROWS / 16;            // m-frags per wave
  constexpr int SLOTS = ROWS * KTOT / 8;   // 16B LDS slots
  constexpr int NLD = SLOTS / 256;         // stage loads per thread
  constexpr int RSH = (ROWS == 64) ? 6 : 5;
  __shared__ u16 lds[SLOTS][8];            // slot = g*ROWS + row  (g = k/8)

  const int tid = threadIdx.x;
  const int wave = tid >> 6, lane = tid & 63;
  const int kg = lane >> 4, lr = lane & 15;
  const long b = blockIdx.z;
  const int m0 = blockIdx.x * ROWS, n0 = blockIdx.y * 128;
  A += b * a_bs; Bt += b * b_bs;

  float* out0f = (float*)out0v;
  u16* out0h = (u16*)out0v;
  const float* e0f = (const float*)e0v;
  const u16* e0h = (const u16*)e0v;
  const u16* e1h = (const u16*)e1v;
  const u16* e2h = (const u16*)e2v;

  // --- stage whole A panel, one barrier ---
#pragma unroll
  for (int i = 0; i < NLD; ++i) {
    int s = tid + 256 * i;
    int row = s & (ROWS - 1), g = s >> RSH;
    const u16* src = A + (long)(m0 + row) * lda + g * 8;
    __builtin_amdgcn_global_load_lds(
        (const __attribute__((address_space(1))) void*)src,
        (__attribute__((address_space(3))) void*)&lds[wave * 64 + 256 * i][0],
        16, 0, 0);
  }
  __syncthreads();

  // --- barrier-free K loop: B from L2 into regs ---
  f32x4 acc[MF][2];
#pragma unroll
  for (int m = 0; m < MF; ++m)
#pragma unroll
    for (int n = 0; n < 2; ++n) acc[m][n] = (f32x4){0.f, 0.f, 0.f, 0.f};

  const u16* Bp0 = Bt + (long)(n0 + wave * 32 + lr) * ldb + kg * 8;
  const u16* Bp1 = Bp0 + 16 * ldb;

  constexpr int NK = KTOT / 32;
#pragma unroll 4
  for (int g2 = 0; g2 < NK; ++g2) {
    bf16x8 af[MF], bf[2];
#pragma unroll
    for (int m = 0; m < MF; ++m)
      af[m] = *(const bf16x8*)&lds[(g2 * 4 + kg) * ROWS + m * 16 + lr][0];
    bf[0] = *(const bf16x8*)&Bp0[g2 * 32];
    bf[1] = *(const bf16x8*)&Bp1[g2 * 32];
#pragma unroll
    for (int m = 0; m < MF; ++m)
#pragma unroll
      for (int n = 0; n < 2; ++n)
        acc[m][n] = __builtin_amdgcn_mfma_f32_16x16x32_bf16(af[m], bf[n], acc[m][n], 0, 0, 0);
  }

  // frag elem j -> row = m0 + m*16 + kg*4 + j, col = n0 + wave*32 + n*16 + lr
  if constexpr (MODE == 0) {
    // scores: Pt = exp(S*scale) (zero padded cols), Zp per-block row-sums
    float rs[MF][4];
#pragma unroll
    for (int m = 0; m < MF; ++m)
#pragma unroll
      for (int j = 0; j < 4; ++j) rs[m][j] = 0.f;
#pragma unroll
    for (int m = 0; m < MF; ++m) {
#pragma unroll
      for (int n = 0; n < 2; ++n) {
        int col = n0 + wave * 32 + n * 16 + lr;
#pragma unroll
        for (int j = 0; j < 4; ++j) {
          long row = m0 + m * 16 + kg * 4 + j;
          float p = __expf(acc[m][n][j] * scale);
          bool valid = (col < nvalid);
          out1[b * o1_bs + row * ld1 + col] = valid ? f2bf(p) : (u16)0;
          rs[m][j] += valid ? p : 0.f;
        }
      }
    }
#pragma unroll
    for (int m = 0; m < MF; ++m)
#pragma unroll
      for (int j = 0; j < 4; ++j) {
#pragma unroll
        for (int msk = 1; msk < 16; msk <<= 1)
          rs[m][j] += __shfl_xor(rs[m][j], msk, 64);
      }
    __syncthreads();                       // done reading A from LDS
    float* zbuf = (float*)&lds[0][0];      // [4 waves][64 rows]
    if (lr == 0) {
#pragma unroll
      for (int m = 0; m < MF; ++m)
#pragma unroll
        for (int j = 0; j < 4; ++j)
          zbuf[wave * 64 + m * 16 + kg * 4 + j] = rs[m][j];
    }
    __syncthreads();
    if (tid < 64)
      out0f[b * o0_bs + (long)blockIdx.y * NP + (m0 + tid)] =
          zbuf[tid] + zbuf[64 + tid] + zbuf[128 + tid] + zbuf[192 + tid];
    return;
  }

#pragma unroll
  for (int m = 0; m < MF; ++m) {
#pragma unroll
    for (int n = 0; n < 2; ++n) {
      int col = n0 + wave * 32 + n * 16 + lr;
#pragma unroll
      for (int j = 0; j < 4; ++j) {
        long row = m0 + m * 16 + kg * 4 + j;
        float v = acc[m][n][j];
        if constexpr (MODE == 2) {        // Chru(bf16) = memT @ Wruh^T + bias_ru
          out1[b * o1_bs + row * ld1 + col] = f2bf(v + e0f[col]);
        } else if constexpr (MODE == 3) { // gates r,u (chru bf16, mem bf16)
          float gt = sigmf(v + bf2f(e0h[b * e0_bs + row * 1024 + col]));
          if (col < 512)                  // r -> RH = r*mem into XR cols 512..1023
            out1[b * o1_bs + row * ld1 + 512 + col] =
                f2bf(gt * bf2f(e1h[b * e1_bs + row * 512 + col]));
          else                            // u -> U (bf16)
            out0h[b * o0_bs + row * ld0 + (col - 512)] = f2bf(gt);
        } else if constexpr (MODE == 4) { // candidate + GRU update
          float cg = tanh_fast(v + e0f[col]);
          float u = bf2f(e1h[b * e1_bs + row * 512 + col]);
          float mm = bf2f(e2h[b * e2_bs + row * 512 + col]);
          float x = mm * (1.f - u) + u * cg;
          out1[b * o1_bs + row * ld1 + col] = f2bf(x);
          if (out0f) out0f[b * o0_bs + row * ld0 + col] = x;
        }
      }
    }
  }
}

// ---------- mem GEMM: Ppart[b,z] = Pt(k-chunk z) @ moutb^T, BN=512 ----------
// grid (26, PVSPLIT, NB); A (Pt) LDS double-buffered; B (moutb) streamed
// global->reg from L2 with one-step register prefetch.
__global__ __launch_bounds__(256, 2)
void gemm_pv(const u16* __restrict__ Pt, const u16* __restrict__ moutb,
             u16* __restrict__ Ppart)
{
  const int m0 = blockIdx.x * 64;
  const int z = blockIdx.y;
  const int b = blockIdx.z;
  const int k0 = z * PVKC;               // 28 steps of 32

  const u16* A = Pt + (long)b * NP * KP;
  const u16* B0;
  {
    const u16* Bb = moutb + (long)b * DO_ * KP;
    B0 = Bb + (long)((threadIdx.x >> 6) * 128 + (threadIdx.x & 15)) * KP +
         ((threadIdx.x & 63) >> 4) * 8;
  }

  __shared__ u16 lds[2][2048];           // [buf][g(4)][row(64)][8]
  const int tid = threadIdx.x;
  const int wave = tid >> 6, lane = tid & 63;
  const int kg = lane >> 4, lr = lane & 15;

  auto stage = [&](int buf, int kt) {
    int row = tid & 63, g = tid >> 6;
    const u16* src = A + (long)(m0 + row) * KP + kt + g * 8;
    __builtin_amdgcn_global_load_lds(
        (const __attribute__((address_space(1))) void*)src,
        (__attribute__((address_space(3))) void*)&lds[buf][(wave * 64) * 8],
        16, 0, 0);
  };

  f32x4 acc[4][8];
#pragma unroll
  for (int m = 0; m < 4; ++m)
#pragma unroll
    for (int n = 0; n < 8; ++n) acc[m][n] = (f32x4){0.f, 0.f, 0.f, 0.f};

  bf16x8 bra[8], brb[8];
#pragma unroll
  for (int n = 0; n < 8; ++n)
    bra[n] = *(const bf16x8*)&B0[(long)n * 16 * KP + k0];
  stage(0, k0);
  __syncthreads();

#define PV_STEP(BU, BL, T, CUR)                                                  \
  {                                                                              \
    if ((T) + 1 < 28) {                                                          \
      int ktn = k0 + ((T) + 1) * 32;                                             \
      _Pragma("unroll") for (int n = 0; n < 8; ++n)                              \
          BL[n] = *(const bf16x8*)&B0[(long)n * 16 * KP + ktn];                  \
      stage((CUR) ^ 1, ktn);                                                     \
    }                                                                            \
    bf16x8 af[4];                                                                \
    _Pragma("unroll") for (int m = 0; m < 4; ++m)                                \
        af[m] = *(const bf16x8*)&lds[CUR][(kg * 64 + m * 16 + lr) * 8];          \
    _Pragma("unroll") for (int m = 0; m < 4; ++m)                                \
        _Pragma("unroll") for (int n = 0; n < 8; ++n)                            \
            acc[m][n] = __builtin_amdgcn_mfma_f32_16x16x32_bf16(af[m], BU[n],    \
                                                                acc[m][n], 0, 0, 0); \
    __syncthreads();                                                             \
  }

  for (int tp = 0; tp < 14; ++tp) {
    PV_STEP(bra, brb, 2 * tp, 0);
    PV_STEP(brb, bra, 2 * tp + 1, 1);
  }
#undef PV_STEP

  // write bf16 partial tile [64][512]
  u16* out = Ppart + (long)(b * PVSPLIT + z) * NP * DO_;
#pragma unroll
  for (int m = 0; m < 4; ++m) {
#pragma unroll
    for (int n = 0; n < 8; ++n) {
      int col = wave * 128 + n * 16 + lr;
#pragma unroll
      for (int j = 0; j < 4; ++j) {
        int row = m0 + m * 16 + kg * 4 + j;
        out[(long)row * DO_ + col] = f2bf(acc[m][n][j]);
      }
    }
  }
}

// ---------- small kernels ----------
// transpose+cast: in f32 [R][C] -> out bf16 [Cp][out_ld], out[c][r] = in[r][c], pad 0
__global__ void k_transpose_cast(const float* __restrict__ in, u16* __restrict__ out,
                                 int R, int C, int Cp, int out_ld,
                                 long in_bs, long out_bs) {
  __shared__ float t[32][33];
  long b = blockIdx.z;
  int c0 = blockIdx.x * 32, r0 = blockIdx.y * 32;
  int tx = threadIdx.x, ty = threadIdx.y;
#pragma unroll
  for (int i = 0; i < 32; i += 8) {
    int r = r0 + ty + i, c = c0 + tx;
    t[ty + i][tx] = (r < R && c < C) ? in[b * in_bs + (long)r * C + c] : 0.f;
  }
  __syncthreads();
#pragma unroll
  for (int i = 0; i < 32; i += 8) {
    int c = c0 + ty + i, r = r0 + tx;
    if (c < Cp && r < R)
      out[b * out_bs + (long)c * out_ld + r] = f2bf(t[tx][ty + i]);
  }
}

// cast f32 [R][Cin] -> bf16 [R][Cout] with zero pad
__global__ void k_cast_pad(const float* __restrict__ in, u16* __restrict__ out,
                           int Cin, int Cout, long in_bs, long out_bs) {
  int c = blockIdx.x * 256 + threadIdx.x;
  int r = blockIdx.y;
  long b = blockIdx.z;
  if (c >= Cout) return;
  out[b * out_bs + (long)r * Cout + c] =
      (c < Cin) ? f2bf(in[b * in_bs + (long)r * Cin + c]) : (u16)0;
}

__global__ void k_build_wru(const float* __restrict__ wr_, const float* __restrict__ wu_,
                            u16* __restrict__ wrux, u16* __restrict__ wruh) {
  int k = blockIdx.x * 256 + threadIdx.x;  // 0..511
  int m = blockIdx.y;                      // 0..1023
  if (k >= 512) return;
  const float* src = (m < 512) ? wr_ : wu_;
  int mm = m & 511;
  wrux[m * 512 + k] = f2bf(src[mm * 1024 + k]);
  wruh[m * 512 + k] = f2bf(src[mm * 1024 + 512 + k]);
}

__global__ void k_bias_ru(const float* __restrict__ br_, const float* __restrict__ bu_,
                          float* __restrict__ bias) {
  int i = blockIdx.x * 256 + threadIdx.x;
  if (i < 1024) bias[i] = (i < 512) ? br_[i] : bu_[i - 512];
}

// invZ[b][q] = 1 / sum_nb Zp[b][nb][q]
__global__ void k_invz(const float* __restrict__ Zp, float* __restrict__ invZ) {
  int t = blockIdx.x * 256 + threadIdx.x;
  if (t >= NB * NP) return;
  int b = t / NP, q = t - b * NP;
  const float* base = Zp + (long)b * 49 * NP + q;
  float s = 0.f;
#pragma unroll
  for (int nb = 0; nb < 49; ++nb) s += base[(long)nb * NP];
  invZ[t] = 1.f / s;
}

// memTb[b][q][o] = bf16( invZ[b][q] * sum_{z<PVSPLIT} Ppart[b*PVSPLIT+z][q][o] )
__global__ void k_reduce_mem(const u16* __restrict__ Ppart, const float* __restrict__ invZ,
                             u16* __restrict__ memTb) {
  long t = (long)blockIdx.x * 256 + threadIdx.x;   // uint4 index (8 bf16)
  const long bs = (long)NP * DO_;
  if (t >= (long)NB * bs / 8) return;
  long flat = t * 8;
  int b = (int)(flat / bs);
  long r = flat - (long)b * bs;
  int q = (int)(r / DO_);
  float s[8];
#pragma unroll
  for (int e = 0; e < 8; ++e) s[e] = 0.f;
#pragma unroll
  for (int z = 0; z < PVSPLIT; ++z) {
    uint4 v = *(const uint4*)&Ppart[(long)(b * PVSPLIT + z) * bs + r];
    s[0] += bf2f((u16)(v.x & 0xffff)); s[1] += bf2f((u16)(v.x >> 16));
    s[2] += bf2f((u16)(v.y & 0xffff)); s[3] += bf2f((u16)(v.y >> 16));
    s[4] += bf2f((u16)(v.z & 0xffff)); s[5] += bf2f((u16)(v.z >> 16));
    s[6] += bf2f((u16)(v.w & 0xffff)); s[7] += bf2f((u16)(v.w >> 16));
  }
  float iz = invZ[b * NP + q];
  uint4 o;
  o.x = (unsigned)f2bf(s[0] * iz) | ((unsigned)f2bf(s[1] * iz) << 16);
  o.y = (unsigned)f2bf(s[2] * iz) | ((unsigned)f2bf(s[3] * iz) << 16);
  o.z = (unsigned)f2bf(s[4] * iz) | ((unsigned)f2bf(s[5] * iz) << 16);
  o.w = (unsigned)f2bf(s[6] * iz) | ((unsigned)f2bf(s[7] * iz) << 16);
  *(uint4*)&memTb[(long)b * bs + r] = o;
}

// Qfin [NP][512] f32 -> d_out[b][ch][HW] (first 512 channels)
__global__ void k_out_q(const float* __restrict__ Qfin, float* __restrict__ dout) {
  __shared__ float t[32][33];
  long b = blockIdx.z;
  int q0 = blockIdx.x * 32, ch0 = blockIdx.y * 32;
  int tx = threadIdx.x, ty = threadIdx.y;
#pragma unroll
  for (int i = 0; i < 32; i += 8)
    t[ty + i][tx] = Qfin[b * ((long)NP * 512) + (long)(q0 + ty + i) * 512 + ch0 + tx];
  __syncthreads();
#pragma unroll
  for (int i = 0; i < 32; i += 8) {
    int ch = ch0 + ty + i, q = q0 + tx;
    if (q < HW)
      dout[b * ((long)1024 * HW) + (long)ch * HW + q] = t[tx][ty + i];
  }
}

__global__ void k_copy_q0(const float4* __restrict__ src, float4* __restrict__ dst) {
  int idx = blockIdx.x * 256 + threadIdx.x;
  long b = blockIdx.z;
  const long n4 = (long)DO_ * HW / 4;  // 199680
  if (idx < n4)
    dst[b * ((long)1024 * HW / 4) + n4 + idx] = src[b * n4 + idx];
}

// ---------- host ----------
extern "C" void kernel_launch(void* const* d_in, const int* in_sizes, int n_in,
                              void* d_out, int out_size, void* d_ws, size_t ws_size,
                              hipStream_t stream) {
  const float* m_in  = (const float*)d_in[0];
  const float* m_out = (const float*)d_in[1];
  const float* q_in  = (const float*)d_in[2];
  const float* q_out = (const float*)d_in[3];
  const float* wr    = (const float*)d_in[4];
  const float* br    = (const float*)d_in[5];
  const float* wu    = (const float*)d_in[6];
  const float* bu    = (const float*)d_in[7];
  const float* wc    = (const float*)d_in[8];
  const float* bc    = (const float*)d_in[9];
  float* dout = (float*)d_out;

  // workspace layout (all sizes 256B-multiples)
  char* p = (char*)d_ws;
  size_t off = 0;
  auto alloc = [&](size_t bytes) { void* r = p + off; off += (bytes + 255) & ~(size_t)255; return r; };
  u16*   miT    = (u16*)alloc((size_t)NB * KP * DE * 2);       // [b][k(6272)][d(128)]
  u16*   qiT    = (u16*)alloc((size_t)NB * NP * DE * 2);       // [b][q(1664)][d(128)]
  u16*   Pt     = (u16*)alloc((size_t)NB * NP * KP * 2);       // [b][q][k] = exp(S)
  float* invZ   = (float*)alloc((size_t)NB * NP * 4);
  u16*   moutb  = (u16*)alloc((size_t)NB * DO_ * KP * 2);      // [b][o][k]
  u16*   memTb  = (u16*)alloc((size_t)NB * NP * DO_ * 2);      // [b][q][o] bf16
  // chru,U,XRb,Qfin contiguous: pv partials (28 * NP*DO_*2 = 47.7MB) alias this
  // exact 47.7MB span (all four dead until after k_reduce_mem / last layer).
  u16*   chru   = (u16*)alloc((size_t)NB * NP * 1024 * 2);     // [b][q][1024] bf16
  u16*   U      = (u16*)alloc((size_t)NB * NP * DO_ * 2);      // bf16
  u16*   XRb    = (u16*)alloc((size_t)NB * NP * 1024 * 2);
  float* Qfin   = (float*)alloc((size_t)NB * NP * DO_ * 4);
  u16*   XRa    = (u16*)alloc((size_t)NB * NP * 1024 * 2);     // [b][q][x(512)|rh(512)]
  u16*   wrux   = (u16*)alloc((size_t)1024 * 512 * 2);
  u16*   wruh   = (u16*)alloc((size_t)1024 * 512 * 2);
  u16*   wcb    = (u16*)alloc((size_t)512 * 1024 * 2);
  float* biasru = (float*)alloc((size_t)1024 * 4);
  u16*   Ppart  = (u16*)chru;      // [NB*PVSPLIT][NP][DO_] bf16, alias
  float* Zp     = (float*)memTb;   // [NB][49][NP] f32, alias (dead before memTb write)
  if (off > ws_size) return;  // workspace too small -> fail visibly

  // --- prep: weights ---
  k_build_wru<<<dim3(2, 1024), 256, 0, stream>>>(wr, wu, wrux, wruh);
  k_cast_pad<<<dim3(4, 512, 1), 256, 0, stream>>>(wc, wcb, 1024, 1024, 0, 0);
  k_bias_ru<<<dim3(4), 256, 0, stream>>>(br, bu, biasru);
  // --- prep: inputs ---
  k_cast_pad<<<dim3(25, 512, NB), 256, 0, stream>>>(
      m_out, moutb, THW, KP, (long)DO_ * THW, (long)DO_ * KP);
  k_transpose_cast<<<dim3(196, 4, NB), dim3(32, 8), 0, stream>>>(
      m_in, miT, DE, THW, KP, DE, (long)DE * THW, (long)KP * DE);
  k_transpose_cast<<<dim3(52, 4, NB), dim3(32, 8), 0, stream>>>(
      q_in, qiT, DE, HW, NP, DE, (long)DE * HW, (long)NP * DE);
  k_transpose_cast<<<dim3(52, 16, NB), dim3(32, 8), 0, stream>>>(
      q_out, XRa, DO_, HW, NP, 1024, (long)DO_ * HW, (long)NP * 1024);

  // --- attention scores: Pt[q,k] = exp(qiT·miT^T / sqrt(De)); Zp row-partials ---
  gemm_ws<0, 64, 128><<<dim3(26, 49, NB), 256, 0, stream>>>(
      qiT, miT, DE, DE, (long)NP * DE, (long)KP * DE,
      Zp, (long)49 * NP, 0, Pt, (long)NP * KP, KP,
      nullptr, 0, nullptr, 0, nullptr, 0, THW, 0.08838834764831845f);
  k_invz<<<dim3(26), 256, 0, stream>>>(Zp, invZ);

  // --- mem: Ppart[b,z] = Pt(chunk) @ moutb^T (BN=512, split-K x7) ---
  gemm_pv<<<dim3(26, PVSPLIT, NB), 256, 0, stream>>>(Pt, moutb, Ppart);
  k_reduce_mem<<<dim3(1664), 256, 0, stream>>>(Ppart, invZ, memTb);

  // --- Chru(bf16) = memT @ Wruh^T + [br;bu] ---
  gemm_ws<2, 64, 512><<<dim3(26, 8, NB), 256, 0, stream>>>(
      memTb, wruh, DO_, DO_, (long)NP * DO_, 0,
      nullptr, 0, 0, chru, (long)NP * 1024, 1024,
      biasru, 0, nullptr, 0, nullptr, 0, 0, 0.f);

  // --- GRU layers ---
  u16* xr[2] = {XRa, XRb};
  for (int l = 0; l < PROP; ++l) {
    u16* cur = xr[l & 1];
    u16* nxt = xr[(l + 1) & 1];
    // gates r,u: sigmoid(X @ Wrux^T + chru); r*mem -> cur cols 512.., u -> U
    gemm_ws<3, 64, 512><<<dim3(26, 8, NB), 256, 0, stream>>>(
        cur, wrux, 1024, DO_, (long)NP * 1024, 0,
        U, (long)NP * DO_, DO_, cur, (long)NP * 1024, 1024,
        chru, (long)NP * 1024, memTb, (long)NP * DO_, nullptr, 0, 0, 0.f);
    // candidate + update: x' = mem*(1-u) + u*tanh(XR @ wc^T + bc)
    gemm_ws<4, 32, 1024><<<dim3(52, 4, NB), 256, 0, stream>>>(
        cur, wcb, 1024, 1024, (long)NP * 1024, 0,
        (l == PROP - 1) ? (void*)Qfin : nullptr, (long)NP * DO_, DO_,
        nxt, (long)NP * 1024, 1024,
        bc, 0, U, (long)NP * DO_, memTb, (long)NP * DO_, 0, 0.f);
  }

  // --- outputs ---
  k_out_q<<<dim3(49, 16, NB), dim3(32, 8), 0, stream>>>(Qfin, dout);
  k_copy_q0<<<dim3(780, 1, NB), 256, 0, stream>>>((const float4*)q_out, (float4*)dout);
}